// Round 1
// 529.425 us; speedup vs baseline: 1.0168x; 1.0168x over previous
//
#include <hip/hip_runtime.h>

typedef __attribute__((ext_vector_type(8))) short short8;
typedef __attribute__((ext_vector_type(4))) float f32x4;

#define MFMA16(a, b, c) __builtin_amdgcn_mfma_f32_16x16x32_bf16((a), (b), (c), 0, 0, 0)

constexpr int Bv  = 32;    // batch
constexpr int Lv  = 168;   // encoder length
constexpr int Sv  = 512;   // sites
constexpr int HZv = 24;    // horizon
constexpr int Mv  = 32;    // sequences per block (512 blocks, 2 per CU)
constexpr int HSTR = 88;   // h-row stride (shorts)
constexpr int HBUF = Mv * HSTR;   // 2816 shorts per buffer
// LDS pad: push static LDS to ~54 KB so AT MOST 2 blocks fit per CU (160 KB).
// 512 blocks / 256 CUs = exactly 2 each -> forced balanced placement, two
// INDEPENDENT barrier domains per CU (fills the 30% VALU-idle co-stall).
constexpr int PADv = 16000;

__device__ __forceinline__ float b2f(short s) {
    unsigned u = ((unsigned)(unsigned short)s) << 16;
    return __builtin_bit_cast(float, u);
}
__device__ __forceinline__ short f2b(float f) {
    unsigned u = __builtin_bit_cast(unsigned, f);
    unsigned r = (u + 0x7FFFu + ((u >> 16) & 1u)) >> 16;   // RNE
    return (short)(unsigned short)r;
}
// no clamps: exp2(inf)=inf, rcp(inf)=0 give exact saturation, no NaN path
__device__ __forceinline__ float sigm(float x) {
    float e = __builtin_amdgcn_exp2f(-1.44269504088896f * x);
    return __builtin_amdgcn_rcpf(1.0f + e);
}
__device__ __forceinline__ float tanh_(float x) {
    float e = __builtin_amdgcn_exp2f(2.88539008177793f * x); // exp(2x)
    return 1.0f - 2.0f * __builtin_amdgcn_rcpf(e + 1.0f);
}
__device__ __forceinline__ void hi8(const float* __restrict__ p, short8& hi) {
#pragma unroll
    for (int j = 0; j < 8; ++j) hi[j] = f2b(p[j]);
}

// r15: M=32 / 256-thread blocks / grid=512 -> 2 independent barrier domains
// per CU. Hazard structure identical to r14 (ONE barrier per encoder step;
// all cross-step RAW/WAR pairs separated by exactly one barrier). Decoder
// y-projection parallelized over 128 lanes + shfl_xor reduce.
__global__ __launch_bounds__(256, 2)
void sitewise_lstm(const float* __restrict__ x_seq,
                   const float* __restrict__ Wih0, const float* __restrict__ Whh0,
                   const float* __restrict__ bih0, const float* __restrict__ bhh0,
                   const float* __restrict__ Wih1, const float* __restrict__ Whh1,
                   const float* __restrict__ bih1, const float* __restrict__ bhh1,
                   const float* __restrict__ Wcih, const float* __restrict__ Wchh,
                   const float* __restrict__ bcih, const float* __restrict__ bchh,
                   const float* __restrict__ Wout, const float* __restrict__ bout,
                   float* __restrict__ out)
{
    __shared__ __align__(16) short Hhi[4 * HBUF + PADv];   // ~54 KB total
    __shared__ float woutF[64];
    __shared__ float ybufF[Mv];

    const int tid  = threadIdx.x;
    const int wv   = tid >> 6;    // wave = U-slice, 0..3
    const int lane = tid & 63;
    const int q    = lane >> 4;
    const int col  = lane & 15;
    const int U    = wv;          // unit-slice: u in [16U, 16U+16)
    const int bid  = blockIdx.x;
    const int b    = bid >> 4;
    const int s0   = (bid & 15) << 5;
    const int uu   = U * 16 + col;
    const int me   = q * 4;                   // epilogue m base (+ mt*16 + r)

    for (int i = tid; i < 4 * HBUF / 2; i += 256) ((int*)Hhi)[i] = 0;
    if (tid < 64) woutF[tid] = Wout[tid];

    const float* xbF = x_seq + b * Lv * Sv + s0;

    const int roA = col * HSTR + q * 8;       // + kc*32 + mt*16*HSTR
    const int wiA = me * HSTR + uu;           // + (mt*16+r)*HSTR

    // ---- per-wave weights: 4 gate-tiles x 2 kc per matrix, single bf16 (RNE) ----
    short8 Whi[3][4][2];   // [Whh0|Wih1|Whh1][g][kc]; slot0 -> Wchh in decoder
    float bias0[4], bias1[4], biasc[4], wih0gE[4], wcihgE[4];
#pragma unroll
    for (int g = 0; g < 4; ++g) {
        const int j = g * 64 + uu;
        bias0[g] = bih0[j] + bhh0[j];
        bias1[g] = bih1[j] + bhh1[j];
        biasc[g] = bcih[j] + bchh[j];
#pragma unroll
        for (int kc = 0; kc < 2; ++kc) {
            const int off = j * 64 + kc * 32 + q * 8;
            hi8(Whh0 + off, Whi[0][g][kc]);
            hi8(Wih1 + off, Whi[1][g][kc]);
            hi8(Whh1 + off, Whi[2][g][kc]);
        }
        wih0gE[g] = Wih0[j];
        wcihgE[g] = Wcih[j];
    }

    float c0[8], c1[8];
#pragma unroll
    for (int i = 0; i < 8; ++i) { c0[i] = 0.f; c1[i] = 0.f; }

    __syncthreads();

// one fused 2-layer encoder step, ONE barrier; buffer bases are literals
#define ENC_STEP(T, B0P, B0N, B1P, B1N) do {                                          \
        f32x4 xv[2];                                                                  \
        xv[0] = *(const f32x4*)(xbF + (T) * Sv + me);                                 \
        xv[1] = *(const f32x4*)(xbF + (T) * Sv + me + 16);                            \
        short8 ah[2][2];                                                              \
        _Pragma("unroll")                                                             \
        for (int kc = 0; kc < 2; ++kc)                                                \
            _Pragma("unroll")                                                         \
            for (int mt = 0; mt < 2; ++mt)                                            \
                ah[kc][mt] = *(const short8*)(Hhi + (B0P) + roA + kc * 32 + mt * 16 * HSTR); \
        f32x4 pre0[4][2];                                                             \
        _Pragma("unroll")                                                             \
        for (int g = 0; g < 4; ++g)                                                   \
            _Pragma("unroll")                                                         \
            for (int mt = 0; mt < 2; ++mt)                                            \
                pre0[g][mt] = (f32x4){bias0[g], bias0[g], bias0[g], bias0[g]};        \
        _Pragma("unroll")                                                             \
        for (int g = 0; g < 4; ++g)                                                   \
            _Pragma("unroll")                                                         \
            for (int mt = 0; mt < 2; ++mt) pre0[g][mt] = MFMA16(ah[0][mt], Whi[0][g][0], pre0[g][mt]); \
        _Pragma("unroll")                                                             \
        for (int g = 0; g < 4; ++g)                                                   \
            _Pragma("unroll")                                                         \
            for (int mt = 0; mt < 2; ++mt) pre0[g][mt] = MFMA16(ah[1][mt], Whi[0][g][1], pre0[g][mt]); \
        _Pragma("unroll")                                                             \
        for (int mt = 0; mt < 2; ++mt)                                                \
            _Pragma("unroll")                                                         \
            for (int r = 0; r < 4; ++r) {                                             \
                const float xw = xv[mt][r];                                           \
                const float ig = sigm (pre0[0][mt][r] + xw * wih0gE[0]);              \
                const float fg = sigm (pre0[1][mt][r] + xw * wih0gE[1]);              \
                const float gt = tanh_(pre0[2][mt][r] + xw * wih0gE[2]);              \
                const float og = sigm (pre0[3][mt][r] + xw * wih0gE[3]);              \
                const float c  = fg * c0[mt * 4 + r] + ig * gt;                       \
                c0[mt * 4 + r] = c;                                                   \
                Hhi[(B0N) + wiA + (mt * 16 + r) * HSTR] = f2b(og * tanh_(c));         \
            }                                                                         \
        __syncthreads();   /* the ONLY barrier: h0(new) visible */                    \
        short8 bh[2][2], dh[2][2];                                                    \
        _Pragma("unroll")                                                             \
        for (int kc = 0; kc < 2; ++kc)                                                \
            _Pragma("unroll")                                                         \
            for (int mt = 0; mt < 2; ++mt) {                                          \
                bh[kc][mt] = *(const short8*)(Hhi + (B0N) + roA + kc * 32 + mt * 16 * HSTR); \
                dh[kc][mt] = *(const short8*)(Hhi + (B1P) + roA + kc * 32 + mt * 16 * HSTR); \
            }                                                                         \
        f32x4 pre1[4][2];                                                             \
        _Pragma("unroll")                                                             \
        for (int g = 0; g < 4; ++g)                                                   \
            _Pragma("unroll")                                                         \
            for (int mt = 0; mt < 2; ++mt)                                            \
                pre1[g][mt] = (f32x4){bias1[g], bias1[g], bias1[g], bias1[g]};        \
        _Pragma("unroll")                                                             \
        for (int g = 0; g < 4; ++g)                                                   \
            _Pragma("unroll")                                                         \
            for (int mt = 0; mt < 2; ++mt) pre1[g][mt] = MFMA16(bh[0][mt], Whi[1][g][0], pre1[g][mt]); \
        _Pragma("unroll")                                                             \
        for (int g = 0; g < 4; ++g)                                                   \
            _Pragma("unroll")                                                         \
            for (int mt = 0; mt < 2; ++mt) pre1[g][mt] = MFMA16(bh[1][mt], Whi[1][g][1], pre1[g][mt]); \
        _Pragma("unroll")                                                             \
        for (int g = 0; g < 4; ++g)                                                   \
            _Pragma("unroll")                                                         \
            for (int mt = 0; mt < 2; ++mt) pre1[g][mt] = MFMA16(dh[0][mt], Whi[2][g][0], pre1[g][mt]); \
        _Pragma("unroll")                                                             \
        for (int g = 0; g < 4; ++g)                                                   \
            _Pragma("unroll")                                                         \
            for (int mt = 0; mt < 2; ++mt) pre1[g][mt] = MFMA16(dh[1][mt], Whi[2][g][1], pre1[g][mt]); \
        _Pragma("unroll")                                                             \
        for (int mt = 0; mt < 2; ++mt)                                                \
            _Pragma("unroll")                                                         \
            for (int r = 0; r < 4; ++r) {                                             \
                const float ig = sigm (pre1[0][mt][r]);                               \
                const float fg = sigm (pre1[1][mt][r]);                               \
                const float gt = tanh_(pre1[2][mt][r]);                               \
                const float og = sigm (pre1[3][mt][r]);                               \
                const float c  = fg * c1[mt * 4 + r] + ig * gt;                       \
                c1[mt * 4 + r] = c;                                                   \
                Hhi[(B1N) + wiA + (mt * 16 + r) * HSTR] = f2b(og * tanh_(c));         \
            }                                                                         \
        /* no barrier 2: h1new visibility is provided by next step's barrier,  */     \
        /* which sits before the only B1n reader (next phase 2b)               */     \
    } while (0)

    for (int t = 0; t < Lv; t += 2) {
        ENC_STEP(t,     0 * HBUF, 1 * HBUF, 2 * HBUF, 3 * HBUF);
        ENC_STEP(t + 1, 1 * HBUF, 0 * HBUF, 3 * HBUF, 2 * HBUF);
    }
#undef ENC_STEP

    // ================= decoder =================
#pragma unroll
    for (int g = 0; g < 4; ++g)
#pragma unroll
        for (int kc = 0; kc < 2; ++kc)
            hi8(Wchh + (g * 64 + uu) * 64 + kc * 32 + q * 8, Whi[0][g][kc]);
    if (tid < Mv) ybufF[tid] = xbF[(Lv - 1) * Sv + tid];
    __syncthreads();   // h1(final, buf 2) + ybufF visible

    const float boutF = bout[0];
    float* outp = out + b * HZv * Sv + s0;

#define DEC_STEP(T, B1P, B1N) do {                                                    \
        short8 ah[2][2];                                                              \
        _Pragma("unroll")                                                             \
        for (int kc = 0; kc < 2; ++kc)                                                \
            _Pragma("unroll")                                                         \
            for (int mt = 0; mt < 2; ++mt)                                            \
                ah[kc][mt] = *(const short8*)(Hhi + (B1P) + roA + kc * 32 + mt * 16 * HSTR); \
        float yv[2][4];                                                               \
        _Pragma("unroll")                                                             \
        for (int mt = 0; mt < 2; ++mt)                                                \
            _Pragma("unroll")                                                         \
            for (int r = 0; r < 4; ++r)                                               \
                yv[mt][r] = ybufF[me + mt * 16 + r];                                  \
        f32x4 prc[4][2];                                                              \
        _Pragma("unroll")                                                             \
        for (int g = 0; g < 4; ++g)                                                   \
            _Pragma("unroll")                                                         \
            for (int mt = 0; mt < 2; ++mt)                                            \
                prc[g][mt] = (f32x4){biasc[g], biasc[g], biasc[g], biasc[g]};         \
        _Pragma("unroll")                                                             \
        for (int g = 0; g < 4; ++g)                                                   \
            _Pragma("unroll")                                                         \
            for (int mt = 0; mt < 2; ++mt) prc[g][mt] = MFMA16(ah[0][mt], Whi[0][g][0], prc[g][mt]); \
        _Pragma("unroll")                                                             \
        for (int g = 0; g < 4; ++g)                                                   \
            _Pragma("unroll")                                                         \
            for (int mt = 0; mt < 2; ++mt) prc[g][mt] = MFMA16(ah[1][mt], Whi[0][g][1], prc[g][mt]); \
        _Pragma("unroll")                                                             \
        for (int mt = 0; mt < 2; ++mt)                                                \
            _Pragma("unroll")                                                         \
            for (int r = 0; r < 4; ++r) {                                             \
                const float xw = yv[mt][r];                                           \
                const float ig = sigm (prc[0][mt][r] + xw * wcihgE[0]);               \
                const float fg = sigm (prc[1][mt][r] + xw * wcihgE[1]);               \
                const float gt = tanh_(prc[2][mt][r] + xw * wcihgE[2]);               \
                const float og = sigm (prc[3][mt][r] + xw * wcihgE[3]);               \
                const float c  = fg * c1[mt * 4 + r] + ig * gt;                       \
                c1[mt * 4 + r] = c;                                                   \
                Hhi[(B1N) + wiA + (mt * 16 + r) * HSTR] = f2b(og * tanh_(c));         \
            }                                                                         \
        __syncthreads();   /* h(new) visible for y projection */                      \
        if (tid < 128) {   /* waves 0,1: 4 lanes per m, 16 k each, shfl reduce */     \
            const int m  = tid >> 2;                                                  \
            const int pp = tid & 3;                                                   \
            float s = 0.f;                                                            \
            _Pragma("unroll")                                                         \
            for (int k = 0; k < 16; ++k)                                              \
                s += b2f(Hhi[(B1N) + m * HSTR + pp * 16 + k]) * woutF[pp * 16 + k];   \
            s += __shfl_xor(s, 1, 64);                                                \
            s += __shfl_xor(s, 2, 64);                                                \
            if (pp == 0) {                                                            \
                const float y = s + boutF;                                            \
                outp[(T) * Sv + m] = y;                                               \
                ybufF[m] = y;                                                         \
            }                                                                         \
        }                                                                             \
        __syncthreads();   /* ybufF visible for next step */                          \
    } while (0)

    for (int t = 0; t < HZv; t += 2) {
        DEC_STEP(t,     2 * HBUF, 3 * HBUF);
        DEC_STEP(t + 1, 3 * HBUF, 2 * HBUF);
    }
#undef DEC_STEP
}

extern "C" void kernel_launch(void* const* d_in, const int* in_sizes, int n_in,
                              void* d_out, int out_size, void* d_ws, size_t ws_size,
                              hipStream_t stream)
{
    const float* x_seq = (const float*)d_in[0];
    const float* Wih0  = (const float*)d_in[1];
    const float* Whh0  = (const float*)d_in[2];
    const float* bih0  = (const float*)d_in[3];
    const float* bhh0  = (const float*)d_in[4];
    const float* Wih1  = (const float*)d_in[5];
    const float* Whh1  = (const float*)d_in[6];
    const float* bih1  = (const float*)d_in[7];
    const float* bhh1  = (const float*)d_in[8];
    const float* Wcih  = (const float*)d_in[9];
    const float* Wchh  = (const float*)d_in[10];
    const float* bcih  = (const float*)d_in[11];
    const float* bchh  = (const float*)d_in[12];
    const float* Wout  = (const float*)d_in[13];
    const float* bout  = (const float*)d_in[14];
    float* out = (float*)d_out;

    hipLaunchKernelGGL(sitewise_lstm, dim3(Bv * (Sv / Mv)), dim3(256), 0, stream,
                       x_seq, Wih0, Whh0, bih0, bhh0, Wih1, Whh1, bih1, bhh1,
                       Wcih, Wchh, bcih, bchh, Wout, bout, out);
}